// Round 17
// baseline (111.609 us; speedup 1.0000x reference)
//
#include <hip/hip_runtime.h>

#define T_FRAMES 1001
#define MEL_STRIDE 1008
#define P_STRIDE 268

// ws float offsets
#define OFF_WIN 0          // [416] f32
#define OFF_DCT 416        // [64][20] f32
#define OFF_BG  1696       // u16[13 ktile][16384] twiddles, chunked (106496 f)
#define OFF_FBG 108192     // u16[64 mel][264] (8448 f)
#define OFF_MEL 13748128   // f32 [4096][1008]

typedef unsigned int u32;
typedef unsigned short u16;
typedef __attribute__((ext_vector_type(8))) short bf16x8;
typedef __attribute__((ext_vector_type(4))) float f32x4;

__device__ __forceinline__ u16 f2bf(float f) {
  u32 u = __float_as_uint(f);
  u32 r = (u + 0x7FFFu + ((u >> 16) & 1u)) >> 16;
  return (u16)r;
}

__device__ __forceinline__ int reflect_idx(int g) {
  g = (g < 0) ? -g : g;
  g = (g >= 160000) ? (319998 - g) : g;
  return g;
}

__global__ __launch_bounds__(256) void k_init(float* __restrict__ ws) {
  float* win = ws + OFF_WIN;
  float* dct = ws + OFF_DCT;
  u16* bg = (u16*)(ws + OFF_BG);
  u16* fbg = (u16*)(ws + OFF_FBG);
  const float W = 6.28318530717958647692f / 400.0f;
  int tid = blockIdx.x * 256 + threadIdx.x;
  int stride = gridDim.x * 256;
  for (int i = tid; i < 416; i += stride)
    win[i] = (i < 400) ? (0.5f - 0.5f * cosf((float)i * W)) : 0.0f;
  for (int i = tid; i < 64 * 20; i += stride) {
    int m = i / 20, k = i % 20;
    float v = cosf(3.14159265358979323846f / 64.0f * ((float)m + 0.5f) * (float)k) * sqrtf(2.0f / 64.0f);
    if (k == 0) v *= 0.70710678118654752440f;
    dct[i] = v;
  }
  // twiddles, chunked: u16 index = kt*16384 + g*512 + khalf*128 + c15*8 + e
  for (int i = tid; i < 13 * 16384; i += stride) {
    int kt = i >> 14;
    int r = i & 16383;
    int g = r >> 9;
    int khalf = (r >> 7) & 3;
    int c15 = (r >> 3) & 15;
    int e = r & 7;
    int col = g * 16 + c15;
    int n = kt * 32 + khalf * 8 + e;
    int bin = ((col >> 5) << 4) | (col & 15);
    int type = (col >> 4) & 1;
    float v = 0.0f;
    if (n < 400 && bin <= 200) {
      float a = (float)((n * bin) % 400) * W;
      v = type ? -sinf(a) : cosf(a);
    }
    bg[i] = f2bf(v);
  }
  // mel filterbank [mel][264], zero past bin 200
  for (int i = tid; i < 64 * 264; i += stride) {
    int m = i / 264, f = i % 264;
    float v = 0.0f;
    if (f <= 200) {
      float freq = 40.0f * (float)f;
      float m_max = 2595.0f * log10f(1.0f + 8000.0f / 700.0f);
      float ms = m_max / 65.0f;
      float fp0 = 700.0f * (powf(10.0f, (float)(m)     * ms / 2595.0f) - 1.0f);
      float fp1 = 700.0f * (powf(10.0f, (float)(m + 1) * ms / 2595.0f) - 1.0f);
      float fp2 = 700.0f * (powf(10.0f, (float)(m + 2) * ms / 2595.0f) - 1.0f);
      float dn = (freq - fp0) / (fp1 - fp0);
      float up = (fp2 - freq) / (fp2 - fp1);
      v = fmaxf(0.0f, fminf(dn, up));
    }
    fbg[i] = f2bf(v);
  }
}

// One block = 64 frames of one batch row; 512 threads = 8 waves (2M x 4N),
// wave = 32 frames x 128 cols, acc[2][8] (64 AGPR). Total regs/wave <= 128
// -> 16 waves/CU (2 blocks co-resident: LDS 53KB x 2 = 106KB <= 160KB).
// r15 post-mortem: acc[4][8] = 252 total regs/wave capped occupancy at 8
// waves/CU (20%); phases had nothing to overlap. This trades per-wave tile
// for 2x TLP. Inner loop holds ONE bfr (r14 pattern) for low arch-VGPR.
// A (windowed frames) built once into LDS (52 KB, all 13 ktiles); B frags
// global->reg (coalesced 1KB chunks, L2-resident); P = re^2+im^2 overlays A;
// GEMM2 swapped operands -> D[m][frame] direct store.
__global__ __launch_bounds__(512, 4) void k_gemm(const float* __restrict__ wav,
                                                 const float* __restrict__ ws,
                                                 float* __restrict__ mel) {
  extern __shared__ char sm[];  // A: [13 kt][4096 B]; P overlays
  const char* Bg = (const char*)(ws + OFF_BG);
  const u16* FBg = (const u16*)(ws + OFF_FBG);  // [64 mel][264]
  const float* win = ws + OFF_WIN;
  int tid = threadIdx.x, wid = tid >> 6, lane = tid & 63;
  int wm = wid >> 2, wn = wid & 3;
  int bx = blockIdx.x, b = blockIdx.y;
  const float* wv = wav + (size_t)b * 160000;

  // ---- A build, all 13 ktiles: 8 lanes per frame row, 4 samples/lane ----
  {
    int kq8 = tid & 7, rowq = tid >> 3;          // rowq 0..63
    int frame = bx * 64 + rowq;
    bool fvalid = (frame <= 1000);
#pragma unroll 4
    for (int kt = 0; kt < 13; ++kt) {
      int n0 = kt * 32 + kq8 * 4;
      int g0 = frame * 160 + n0 - 200;
      float ax0, ax1, ax2, ax3;
      if (fvalid) {
        if (g0 >= 0 && g0 + 3 < 160000) {
          float4 u = *(const float4*)&wv[g0];
          ax0 = u.x; ax1 = u.y; ax2 = u.z; ax3 = u.w;
        } else {
          ax0 = wv[reflect_idx(g0)];
          ax1 = wv[reflect_idx(g0 + 1)];
          ax2 = wv[reflect_idx(g0 + 2)];
          ax3 = wv[reflect_idx(g0 + 3)];
        }
      } else {
        ax0 = ax1 = ax2 = ax3 = 0.0f;
      }
      float4 w = *(const float4*)&win[n0];
      uint2 pk;
      pk.x = (u32)f2bf(ax0 * w.x) | ((u32)f2bf(ax1 * w.y) << 16);
      pk.y = (u32)f2bf(ax2 * w.z) | ((u32)f2bf(ax3 * w.w) << 16);
      *(uint2*)(sm + kt * 4096 + (kq8 >> 1) * 1024 + rowq * 16 + (kq8 & 1) * 8) = pk;
    }
  }
  __syncthreads();

  // ---- GEMM1: barrier-free K-loop; wave (wm,wn): rows wm*32+32, cols wn*128+128
  f32x4 acc[2][8];
  const f32x4 zf = {0.0f, 0.0f, 0.0f, 0.0f};
#pragma unroll
  for (int mi = 0; mi < 2; ++mi)
#pragma unroll
    for (int nf = 0; nf < 8; ++nf) acc[mi][nf] = zf;

#pragma unroll
  for (int kt = 0; kt < 13; ++kt) {
    bf16x8 af0 = *(const bf16x8*)(sm + kt * 4096 + (lane >> 4) * 1024 +
                                  (wm * 32 + (lane & 15)) * 16);
    bf16x8 af1 = *(const bf16x8*)(sm + kt * 4096 + (lane >> 4) * 1024 +
                                  (wm * 32 + 16 + (lane & 15)) * 16);
#pragma unroll
    for (int nf = 0; nf < 8; ++nf) {
      bf16x8 bfr = *(const bf16x8*)(Bg + kt * 32768 + (wn * 8 + nf) * 1024 + lane * 16);
      acc[0][nf] = __builtin_amdgcn_mfma_f32_16x16x32_bf16(af0, bfr, acc[0][nf], 0, 0, 0);
      acc[1][nf] = __builtin_amdgcn_mfma_f32_16x16x32_bf16(af1, bfr, acc[1][nf], 0, 0, 0);
    }
  }
  __syncthreads();  // all A reads done before P overwrites the region

  // ---- P = re^2+im^2 (bf16) @ LDS 0, stride 268 ----
  u16* P = (u16*)sm;  // [64 frame][268]
#pragma unroll
  for (int mi = 0; mi < 2; ++mi)
#pragma unroll
    for (int i = 0; i < 4; ++i)
#pragma unroll
      for (int r = 0; r < 4; ++r) {
        int row = wm * 32 + mi * 16 + (lane >> 4) * 4 + r;  // frame
        int bin = wn * 64 + i * 16 + (lane & 15);           // freq bin
        float re = acc[mi][2 * i][r], im = acc[mi][2 * i + 1][r];
        P[row * P_STRIDE + bin] = f2bf(re * re + im * im);
      }
  __syncthreads();

  // ---- GEMM2 (swapped): D[m][frame] = FB[m][bins] x P^T[bins][frame]
  // wave: frame group fg = wid&3 (16 frames), mel half mh = (wid>>2)*32.
  int fg = wid & 3, mh = (wid >> 2) * 32;
  f32x4 macc[2];
#pragma unroll
  for (int nf = 0; nf < 2; ++nf) macc[nf] = zf;
#pragma unroll
  for (int kt = 0; kt < 8; ++kt) {
    int krow = kt * 32 + (lane >> 4) * 8;
    bf16x8 pb = *(const bf16x8*)&P[(fg * 16 + (lane & 15)) * P_STRIDE + krow];
#pragma unroll
    for (int nf = 0; nf < 2; ++nf) {
      bf16x8 fa = *(const bf16x8*)&FBg[(mh + nf * 16 + (lane & 15)) * 264 + krow];
      macc[nf] = __builtin_amdgcn_mfma_f32_16x16x32_bf16(fa, pb, macc[nf], 0, 0, 0);
    }
  }

  // ---- direct store: D col = frame, row = m ----
  int t = bx * 64 + fg * 16 + (lane & 15);
  if (t <= 1000) {
#pragma unroll
    for (int nf = 0; nf < 2; ++nf)
#pragma unroll
      for (int r = 0; r < 4; ++r) {
        int m = mh + nf * 16 + (lane >> 4) * 4 + r;
        mel[((size_t)b * 64 + m) * MEL_STRIDE + t] = macc[nf][r];
      }
  }
}

// Wave-parallel EMA scan: one wave per (b,m) row, 16 t/lane, affine map compose.
__global__ __launch_bounds__(256) void k_ema(const float* __restrict__ mel,
                                             float* __restrict__ outp) {
  int wid = threadIdx.x >> 6, lane = threadIdx.x & 63;
  int row = blockIdx.x * 4 + wid;  // 0..4095
  const float* src = mel + (size_t)row * MEL_STRIDE + lane * 16;

  float x[16];
  if (lane < 63) {
    float4 v0 = *(const float4*)&src[0];
    float4 v1 = *(const float4*)&src[4];
    float4 v2 = *(const float4*)&src[8];
    float4 v3 = *(const float4*)&src[12];
    x[0] = v0.x; x[1] = v0.y; x[2] = v0.z; x[3] = v0.w;
    x[4] = v1.x; x[5] = v1.y; x[6] = v1.z; x[7] = v1.w;
    x[8] = v2.x; x[9] = v2.y; x[10] = v2.z; x[11] = v2.w;
    x[12] = v3.x; x[13] = v3.y; x[14] = v3.z; x[15] = v3.w;
#pragma unroll
    for (int i = 0; i < 16; ++i)
      if (lane * 16 + i > 1000) x[i] = 0.0f;
  } else {
#pragma unroll
    for (int i = 0; i < 16; ++i) x[i] = 0.0f;
  }

  float B = 0.0f;
#pragma unroll
  for (int i = 0; i < 16; ++i) B = fmaf(0.98f, B, 0.02f * x[i]);
  float A = 1.0f;
#pragma unroll
  for (int i = 0; i < 16; ++i) A *= 0.98f;

#pragma unroll
  for (int d = 1; d < 64; d <<= 1) {
    float Ap = __shfl_up(A, d, 64);
    float Bp = __shfl_up(B, d, 64);
    if (lane >= d) {
      B = fmaf(A, Bp, B);
      A = A * Ap;
    }
  }
  float s = __shfl_up(B, 1, 64);
  if (lane == 0) s = 0.0f;

  float* dst = outp + (size_t)row * 1001 + lane * 16;
#pragma unroll
  for (int i = 0; i < 16; ++i) {
    s = fmaf(0.98f, s, 0.02f * x[i]);
    if (lane * 16 + i <= 1000) dst[i] = log1pf(x[i] / (s + 1e-6f));
  }
}

// mfcc[b][k][t] = sum_m 10*log10(max(mel,1e-10)) * DCT[m][k]
__global__ __launch_bounds__(256) void k_mfcc(const float* __restrict__ mel,
                                              const float* __restrict__ ws,
                                              float* __restrict__ outp) {
  __shared__ float dls[64 * 20];
  const float* dct = ws + OFF_DCT;
  for (int i = threadIdx.x; i < 64 * 20; i += 256) dls[i] = dct[i];
  __syncthreads();
  int b = blockIdx.y;
  int t = blockIdx.x * 256 + threadIdx.x;
  if (t >= T_FRAMES) return;
  float acc[20];
#pragma unroll
  for (int k = 0; k < 20; ++k) acc[k] = 0.0f;
  for (int m = 0; m < 64; ++m) {
    float v = mel[((size_t)b * 64 + m) * MEL_STRIDE + t];
    float db = 10.0f * log10f(fmaxf(v, 1e-10f));
#pragma unroll
    for (int k = 0; k < 20; ++k) acc[k] = fmaf(db, dls[m * 20 + k], acc[k]);
  }
  float* o = outp + (size_t)b * 20 * 1001 + t;
#pragma unroll
  for (int k = 0; k < 20; ++k) o[(size_t)k * 1001] = acc[k];
}

extern "C" void kernel_launch(void* const* d_in, const int* in_sizes, int n_in,
                              void* d_out, int out_size, void* d_ws, size_t ws_size,
                              hipStream_t stream) {
  const float* wav = (const float*)d_in[0];
  float* out = (float*)d_out;
  float* ws = (float*)d_ws;
  float* mel = ws + OFF_MEL;

  hipFuncSetAttribute(reinterpret_cast<const void*>(k_gemm),
                      hipFuncAttributeMaxDynamicSharedMemorySize, 53248);

  hipLaunchKernelGGL(k_init, dim3(64), dim3(256), 0, stream, ws);
  hipLaunchKernelGGL(k_gemm, dim3(16, 64), dim3(512), 53248, stream, wav, ws, mel);
  hipLaunchKernelGGL(k_ema, dim3(1024), dim3(256), 0, stream, mel, out);
  hipLaunchKernelGGL(k_mfcc, dim3(4, 64), dim3(256), 0, stream, mel, ws, out + 4100096);
}

// Round 20
// 102.872 us; speedup vs baseline: 1.0849x; 1.0849x over previous
//
#include <hip/hip_runtime.h>

#define T_FRAMES 1001
#define MEL_STRIDE 1008
#define P_STRIDE 268

// ws float offsets
#define OFF_WIN 0          // [416] f32
#define OFF_DCT 416        // [64][20] f32
#define OFF_BG  1696       // u16[13 ktile][16384] twiddles, chunked (106496 f)
#define OFF_FBG 108192     // u16[64 mel][264] (8448 f)
#define OFF_MEL 13748128   // f32 [4096][1008]

typedef unsigned int u32;
typedef unsigned short u16;
typedef __attribute__((ext_vector_type(8))) short bf16x8;
typedef __attribute__((ext_vector_type(4))) float f32x4;

__device__ __forceinline__ u16 f2bf(float f) {
  u32 u = __float_as_uint(f);
  u32 r = (u + 0x7FFFu + ((u >> 16) & 1u)) >> 16;
  return (u16)r;
}

__device__ __forceinline__ int reflect_idx(int g) {
  g = (g < 0) ? -g : g;
  g = (g >= 160000) ? (319998 - g) : g;
  return g;
}

__global__ __launch_bounds__(256) void k_init(float* __restrict__ ws) {
  float* win = ws + OFF_WIN;
  float* dct = ws + OFF_DCT;
  u16* bg = (u16*)(ws + OFF_BG);
  u16* fbg = (u16*)(ws + OFF_FBG);
  const float W = 6.28318530717958647692f / 400.0f;
  int tid = blockIdx.x * 256 + threadIdx.x;
  int stride = gridDim.x * 256;
  for (int i = tid; i < 416; i += stride)
    win[i] = (i < 400) ? (0.5f - 0.5f * cosf((float)i * W)) : 0.0f;
  for (int i = tid; i < 64 * 20; i += stride) {
    int m = i / 20, k = i % 20;
    float v = cosf(3.14159265358979323846f / 64.0f * ((float)m + 0.5f) * (float)k) * sqrtf(2.0f / 64.0f);
    if (k == 0) v *= 0.70710678118654752440f;
    dct[i] = v;
  }
  // twiddles, chunked: u16 index = kt*16384 + g*512 + khalf*128 + c15*8 + e
  for (int i = tid; i < 13 * 16384; i += stride) {
    int kt = i >> 14;
    int r = i & 16383;
    int g = r >> 9;
    int khalf = (r >> 7) & 3;
    int c15 = (r >> 3) & 15;
    int e = r & 7;
    int col = g * 16 + c15;
    int n = kt * 32 + khalf * 8 + e;
    int bin = ((col >> 5) << 4) | (col & 15);
    int type = (col >> 4) & 1;
    float v = 0.0f;
    if (n < 400 && bin <= 200) {
      float a = (float)((n * bin) % 400) * W;
      v = type ? -sinf(a) : cosf(a);
    }
    bg[i] = f2bf(v);
  }
  // mel filterbank [mel][264], zero past bin 200
  for (int i = tid; i < 64 * 264; i += stride) {
    int m = i / 264, f = i % 264;
    float v = 0.0f;
    if (f <= 200) {
      float freq = 40.0f * (float)f;
      float m_max = 2595.0f * log10f(1.0f + 8000.0f / 700.0f);
      float ms = m_max / 65.0f;
      float fp0 = 700.0f * (powf(10.0f, (float)(m)     * ms / 2595.0f) - 1.0f);
      float fp1 = 700.0f * (powf(10.0f, (float)(m + 1) * ms / 2595.0f) - 1.0f);
      float fp2 = 700.0f * (powf(10.0f, (float)(m + 2) * ms / 2595.0f) - 1.0f);
      float dn = (freq - fp0) / (fp1 - fp0);
      float up = (fp2 - freq) / (fp2 - fp1);
      v = fmaxf(0.0f, fminf(dn, up));
    }
    fbg[i] = f2bf(v);
  }
}

// One block = 128 frames of one batch row; 512 threads = 8 waves.
// GEMM1 partition: 1M x 8N — each wave owns ALL 128 frames (mi 0..7) and a
// slice of bin-groups: waves 0-4 own 2 bingroups, waves 5-7 own 1 (13 total,
// bins 0..207; cols 208-255 are all-zero twiddles and are SKIPPED: -19% MFMA).
// vs r15 (2M x 4N): per-wave B chunk loads/ktile 8 -> 4 (halved exposure) and
// NO cross-wave duplicate B reads (block L2 B-traffic 64KB -> 26KB per ktile).
// acc[8][4] = 128 AGPR + ~50 arch VGPR -> 8 waves/CU (same occupancy as r15).
// A (windowed frames) built once into LDS (104 KB); P = re^2+im^2 overlays A
// (bins 208-255 zero-filled: FB is zero there but stale-LDS NaN*0 = NaN);
// GEMM2 swapped operands -> D[m][frame] direct store.
__global__ __launch_bounds__(512, 2) void k_gemm(const float* __restrict__ wav,
                                                 const float* __restrict__ ws,
                                                 float* __restrict__ mel) {
  extern __shared__ char sm[];  // A: [13 kt][8192 B]; P overlays
  const char* Bg = (const char*)(ws + OFF_BG);
  const u16* FBg = (const u16*)(ws + OFF_FBG);  // [64 mel][264]
  const float* win = ws + OFF_WIN;
  int tid = threadIdx.x, wid = tid >> 6, lane = tid & 63;
  int bx = blockIdx.x, b = blockIdx.y;
  const float* wv = wav + (size_t)b * 160000;

  // ---- A build, all 13 ktiles: 4 lanes per frame row (coalesced reads) ----
  {
    int kq = tid & 3, rowq = tid >> 2;
    int frame = bx * 128 + rowq;
    bool fvalid = (frame <= 1000);
#pragma unroll 4
    for (int kt = 0; kt < 13; ++kt) {
      int n0 = kt * 32 + kq * 8;
      int g0 = frame * 160 + n0 - 200;
      float ax[8];
      if (fvalid) {
        if (g0 >= 0 && g0 + 7 < 160000) {
          float4 u = *(const float4*)&wv[g0];
          float4 v = *(const float4*)&wv[g0 + 4];
          ax[0] = u.x; ax[1] = u.y; ax[2] = u.z; ax[3] = u.w;
          ax[4] = v.x; ax[5] = v.y; ax[6] = v.z; ax[7] = v.w;
        } else {
#pragma unroll
          for (int e = 0; e < 8; ++e) ax[e] = wv[reflect_idx(g0 + e)];
        }
      } else {
#pragma unroll
        for (int e = 0; e < 8; ++e) ax[e] = 0.0f;
      }
      float4 w0 = *(const float4*)&win[n0];
      float4 w1 = *(const float4*)&win[n0 + 4];
      uint4 pk;
      pk.x = (u32)f2bf(ax[0] * w0.x) | ((u32)f2bf(ax[1] * w0.y) << 16);
      pk.y = (u32)f2bf(ax[2] * w0.z) | ((u32)f2bf(ax[3] * w0.w) << 16);
      pk.z = (u32)f2bf(ax[4] * w1.x) | ((u32)f2bf(ax[5] * w1.y) << 16);
      pk.w = (u32)f2bf(ax[6] * w1.z) | ((u32)f2bf(ax[7] * w1.w) << 16);
      *(uint4*)(sm + kt * 8192 + kq * 2048 + rowq * 16) = pk;
    }
  }
  __syncthreads();

  // ---- GEMM1: barrier-free K-loop, 1M x 8N ----
  int NG = (wid < 5) ? 2 : 1;                 // bingroups owned by this wave
  int GB = (wid < 5) ? wid * 2 : wid + 5;     // first bingroup index (0..12)

  f32x4 acc[8][4];  // [mi][2*j + (0=re,1=im)]
  const f32x4 zf = {0.0f, 0.0f, 0.0f, 0.0f};
#pragma unroll
  for (int mi = 0; mi < 8; ++mi)
#pragma unroll
    for (int j = 0; j < 4; ++j) acc[mi][j] = zf;

#pragma unroll
  for (int kt = 0; kt < 13; ++kt) {
    bf16x8 bfr[4];
    bfr[0] = *(const bf16x8*)(Bg + kt * 32768 + (2 * GB) * 1024 + lane * 16);
    bfr[1] = *(const bf16x8*)(Bg + kt * 32768 + (2 * GB + 1) * 1024 + lane * 16);
    if (NG == 2) {
      bfr[2] = *(const bf16x8*)(Bg + kt * 32768 + (2 * GB + 2) * 1024 + lane * 16);
      bfr[3] = *(const bf16x8*)(Bg + kt * 32768 + (2 * GB + 3) * 1024 + lane * 16);
    }
#pragma unroll
    for (int mi = 0; mi < 8; ++mi) {
      bf16x8 af = *(const bf16x8*)(sm + kt * 8192 + (lane >> 4) * 2048 +
                                   (mi * 16 + (lane & 15)) * 16);
      acc[mi][0] = __builtin_amdgcn_mfma_f32_16x16x32_bf16(af, bfr[0], acc[mi][0], 0, 0, 0);
      acc[mi][1] = __builtin_amdgcn_mfma_f32_16x16x32_bf16(af, bfr[1], acc[mi][1], 0, 0, 0);
      if (NG == 2) {
        acc[mi][2] = __builtin_amdgcn_mfma_f32_16x16x32_bf16(af, bfr[2], acc[mi][2], 0, 0, 0);
        acc[mi][3] = __builtin_amdgcn_mfma_f32_16x16x32_bf16(af, bfr[3], acc[mi][3], 0, 0, 0);
      }
    }
  }
  __syncthreads();  // all A reads done before P overwrites the region

  // ---- P = re^2+im^2 (bf16) @ LDS 0, stride 268; zero bins 208..255 ----
  u16* P = (u16*)sm;  // [128 frame][268]
#pragma unroll
  for (int j = 0; j < 2; ++j) {
    if (j < NG) {
      int bin = (GB + j) * 16 + (lane & 15);
#pragma unroll
      for (int mi = 0; mi < 8; ++mi)
#pragma unroll
        for (int r = 0; r < 4; ++r) {
          int row = mi * 16 + (lane >> 4) * 4 + r;
          float re = acc[mi][2 * j][r], im = acc[mi][2 * j + 1][r];
          P[row * P_STRIDE + bin] = f2bf(re * re + im * im);
        }
    }
  }
  {
    u32* P32 = (u32*)sm;  // zero bins 208..255 (u32 idx 104..127 per row)
    for (int i = tid; i < 3072; i += 512) {
      int row = i / 24, c = i - row * 24;
      P32[row * 134 + 104 + c] = 0;
    }
  }
  __syncthreads();

  // ---- GEMM2 (swapped): D[m][frame] = FB[m][bins] x P^T[bins][frame]
  // wave wid owns frames [wid*16, wid*16+16); nf = mel group.
  f32x4 macc[4];
#pragma unroll
  for (int nf = 0; nf < 4; ++nf) macc[nf] = zf;
#pragma unroll
  for (int kt = 0; kt < 8; ++kt) {
    int krow = kt * 32 + (lane >> 4) * 8;
    bf16x8 pb = *(const bf16x8*)&P[(wid * 16 + (lane & 15)) * P_STRIDE + krow];
#pragma unroll
    for (int nf = 0; nf < 4; ++nf) {
      bf16x8 fa = *(const bf16x8*)&FBg[(nf * 16 + (lane & 15)) * 264 + krow];
      macc[nf] = __builtin_amdgcn_mfma_f32_16x16x32_bf16(fa, pb, macc[nf], 0, 0, 0);
    }
  }

  // ---- direct store: D col = frame, row = m ----
  int t = bx * 128 + wid * 16 + (lane & 15);
  if (t <= 1000) {
#pragma unroll
    for (int nf = 0; nf < 4; ++nf)
#pragma unroll
      for (int r = 0; r < 4; ++r) {
        int m = nf * 16 + (lane >> 4) * 4 + r;
        mel[((size_t)b * 64 + m) * MEL_STRIDE + t] = macc[nf][r];
      }
  }
}

// Wave-parallel EMA scan: one wave per (b,m) row, 16 t/lane, affine map compose.
__global__ __launch_bounds__(256) void k_ema(const float* __restrict__ mel,
                                             float* __restrict__ outp) {
  int wid = threadIdx.x >> 6, lane = threadIdx.x & 63;
  int row = blockIdx.x * 4 + wid;  // 0..4095
  const float* src = mel + (size_t)row * MEL_STRIDE + lane * 16;

  float x[16];
  if (lane < 63) {
    float4 v0 = *(const float4*)&src[0];
    float4 v1 = *(const float4*)&src[4];
    float4 v2 = *(const float4*)&src[8];
    float4 v3 = *(const float4*)&src[12];
    x[0] = v0.x; x[1] = v0.y; x[2] = v0.z; x[3] = v0.w;
    x[4] = v1.x; x[5] = v1.y; x[6] = v1.z; x[7] = v1.w;
    x[8] = v2.x; x[9] = v2.y; x[10] = v2.z; x[11] = v2.w;
    x[12] = v3.x; x[13] = v3.y; x[14] = v3.z; x[15] = v3.w;
#pragma unroll
    for (int i = 0; i < 16; ++i)
      if (lane * 16 + i > 1000) x[i] = 0.0f;
  } else {
#pragma unroll
    for (int i = 0; i < 16; ++i) x[i] = 0.0f;
  }

  float B = 0.0f;
#pragma unroll
  for (int i = 0; i < 16; ++i) B = fmaf(0.98f, B, 0.02f * x[i]);
  float A = 1.0f;
#pragma unroll
  for (int i = 0; i < 16; ++i) A *= 0.98f;

#pragma unroll
  for (int d = 1; d < 64; d <<= 1) {
    float Ap = __shfl_up(A, d, 64);
    float Bp = __shfl_up(B, d, 64);
    if (lane >= d) {
      B = fmaf(A, Bp, B);
      A = A * Ap;
    }
  }
  float s = __shfl_up(B, 1, 64);
  if (lane == 0) s = 0.0f;

  float* dst = outp + (size_t)row * 1001 + lane * 16;
#pragma unroll
  for (int i = 0; i < 16; ++i) {
    s = fmaf(0.98f, s, 0.02f * x[i]);
    if (lane * 16 + i <= 1000) dst[i] = log1pf(x[i] / (s + 1e-6f));
  }
}

// mfcc[b][k][t] = sum_m 10*log10(max(mel,1e-10)) * DCT[m][k]
__global__ __launch_bounds__(256) void k_mfcc(const float* __restrict__ mel,
                                              const float* __restrict__ ws,
                                              float* __restrict__ outp) {
  __shared__ float dls[64 * 20];
  const float* dct = ws + OFF_DCT;
  for (int i = threadIdx.x; i < 64 * 20; i += 256) dls[i] = dct[i];
  __syncthreads();
  int b = blockIdx.y;
  int t = blockIdx.x * 256 + threadIdx.x;
  if (t >= T_FRAMES) return;
  float acc[20];
#pragma unroll
  for (int k = 0; k < 20; ++k) acc[k] = 0.0f;
  for (int m = 0; m < 64; ++m) {
    float v = mel[((size_t)b * 64 + m) * MEL_STRIDE + t];
    float db = 10.0f * log10f(fmaxf(v, 1e-10f));
#pragma unroll
    for (int k = 0; k < 20; ++k) acc[k] = fmaf(db, dls[m * 20 + k], acc[k]);
  }
  float* o = outp + (size_t)b * 20 * 1001 + t;
#pragma unroll
  for (int k = 0; k < 20; ++k) o[(size_t)k * 1001] = acc[k];
}

extern "C" void kernel_launch(void* const* d_in, const int* in_sizes, int n_in,
                              void* d_out, int out_size, void* d_ws, size_t ws_size,
                              hipStream_t stream) {
  const float* wav = (const float*)d_in[0];
  float* out = (float*)d_out;
  float* ws = (float*)d_ws;
  float* mel = ws + OFF_MEL;

  hipFuncSetAttribute(reinterpret_cast<const void*>(k_gemm),
                      hipFuncAttributeMaxDynamicSharedMemorySize, 106496);

  hipLaunchKernelGGL(k_init, dim3(64), dim3(256), 0, stream, ws);
  hipLaunchKernelGGL(k_gemm, dim3(8, 64), dim3(512), 106496, stream, wav, ws, mel);
  hipLaunchKernelGGL(k_ema, dim3(1024), dim3(256), 0, stream, mel, out);
  hipLaunchKernelGGL(k_mfcc, dim3(4, 64), dim3(256), 0, stream, mel, ws, out + 4100096);
}

// Round 21
// 89.884 us; speedup vs baseline: 1.2417x; 1.1445x over previous
//
#include <hip/hip_runtime.h>

#define T_FRAMES 1001
#define MEL_STRIDE 1008
#define P_STRIDE 268

// ws float offsets
#define OFF_WIN 0          // [416] f32
#define OFF_DCT 416        // [64][20] f32 (legacy, unused)
#define OFF_BG  1696       // u16[13 ktile][16384] twiddles, chunked (106496 f)
#define OFF_FBG 108192     // u16[64 mel][264] (8448 f)
#define OFF_DCT16 120000   // f16[32 k][64 m] DCT^T, rows 20..31 zero (1024 f)
#define OFF_MEL 13748128   // f32 [4096][1008]

typedef unsigned int u32;
typedef unsigned short u16;
typedef __attribute__((ext_vector_type(8))) short bf16x8;
typedef __attribute__((ext_vector_type(8))) _Float16 f16x8;
typedef __attribute__((ext_vector_type(4))) float f32x4;

__device__ __forceinline__ u16 f2bf(float f) {
  u32 u = __float_as_uint(f);
  u32 r = (u + 0x7FFFu + ((u >> 16) & 1u)) >> 16;
  return (u16)r;
}

__device__ __forceinline__ int reflect_idx(int g) {
  g = (g < 0) ? -g : g;
  g = (g >= 160000) ? (319998 - g) : g;
  return g;
}

__global__ __launch_bounds__(256) void k_init(float* __restrict__ ws) {
  float* win = ws + OFF_WIN;
  float* dct = ws + OFF_DCT;
  u16* bg = (u16*)(ws + OFF_BG);
  u16* fbg = (u16*)(ws + OFF_FBG);
  _Float16* dct16 = (_Float16*)(ws + OFF_DCT16);
  const float W = 6.28318530717958647692f / 400.0f;
  int tid = blockIdx.x * 256 + threadIdx.x;
  int stride = gridDim.x * 256;
  for (int i = tid; i < 416; i += stride)
    win[i] = (i < 400) ? (0.5f - 0.5f * cosf((float)i * W)) : 0.0f;
  for (int i = tid; i < 64 * 20; i += stride) {
    int m = i / 20, k = i % 20;
    float v = cosf(3.14159265358979323846f / 64.0f * ((float)m + 0.5f) * (float)k) * sqrtf(2.0f / 64.0f);
    if (k == 0) v *= 0.70710678118654752440f;
    dct[i] = v;
  }
  // DCT^T in f16: [32 k-rows][64 m], rows >=20 zero (MFMA pad)
  for (int i = tid; i < 32 * 64; i += stride) {
    int k = i >> 6, m = i & 63;
    float v = 0.0f;
    if (k < 20) {
      v = cosf(3.14159265358979323846f / 64.0f * ((float)m + 0.5f) * (float)k) * sqrtf(2.0f / 64.0f);
      if (k == 0) v *= 0.70710678118654752440f;
    }
    dct16[i] = (_Float16)v;
  }
  // twiddles, chunked: u16 index = kt*16384 + g*512 + khalf*128 + c15*8 + e
  for (int i = tid; i < 13 * 16384; i += stride) {
    int kt = i >> 14;
    int r = i & 16383;
    int g = r >> 9;
    int khalf = (r >> 7) & 3;
    int c15 = (r >> 3) & 15;
    int e = r & 7;
    int col = g * 16 + c15;
    int n = kt * 32 + khalf * 8 + e;
    int bin = ((col >> 5) << 4) | (col & 15);
    int type = (col >> 4) & 1;
    float v = 0.0f;
    if (n < 400 && bin <= 200) {
      float a = (float)((n * bin) % 400) * W;
      v = type ? -sinf(a) : cosf(a);
    }
    bg[i] = f2bf(v);
  }
  // mel filterbank [mel][264], zero past bin 200
  for (int i = tid; i < 64 * 264; i += stride) {
    int m = i / 264, f = i % 264;
    float v = 0.0f;
    if (f <= 200) {
      float freq = 40.0f * (float)f;
      float m_max = 2595.0f * log10f(1.0f + 8000.0f / 700.0f);
      float ms = m_max / 65.0f;
      float fp0 = 700.0f * (powf(10.0f, (float)(m)     * ms / 2595.0f) - 1.0f);
      float fp1 = 700.0f * (powf(10.0f, (float)(m + 1) * ms / 2595.0f) - 1.0f);
      float fp2 = 700.0f * (powf(10.0f, (float)(m + 2) * ms / 2595.0f) - 1.0f);
      float dn = (freq - fp0) / (fp1 - fp0);
      float up = (fp2 - freq) / (fp2 - fp1);
      v = fmaxf(0.0f, fminf(dn, up));
    }
    fbg[i] = f2bf(v);
  }
}

// One block = 128 frames of one batch row; 512 threads = 8 waves.
// GEMM1: 1M x 8N, dead-column-trimmed (r20, 60.4us). GEMM2: mel. GEMM3 (new):
// MFCC fused — per wave, db = 10log10(mel tile) -> f16 LDS (stride 72, own
// rows only, no barrier), mfma_f16(DCT16 rows, db rows) -> mfcc direct store.
// Removes the k_mfcc dispatch and its full-mel re-read.
__global__ __launch_bounds__(512, 2) void k_gemm(const float* __restrict__ wav,
                                                 const float* __restrict__ ws,
                                                 float* __restrict__ mel,
                                                 float* __restrict__ mfcc) {
  extern __shared__ char sm[];  // A: [13 kt][8192 B]; P overlays; db @69632
  const char* Bg = (const char*)(ws + OFF_BG);
  const u16* FBg = (const u16*)(ws + OFF_FBG);        // [64 mel][264]
  const _Float16* DCTg = (const _Float16*)(ws + OFF_DCT16);  // [32 k][64 m]
  const float* win = ws + OFF_WIN;
  int tid = threadIdx.x, wid = tid >> 6, lane = tid & 63;
  int bx = blockIdx.x, b = blockIdx.y;
  const float* wv = wav + (size_t)b * 160000;

  // ---- A build, all 13 ktiles: 4 lanes per frame row (coalesced reads) ----
  {
    int kq = tid & 3, rowq = tid >> 2;
    int frame = bx * 128 + rowq;
    bool fvalid = (frame <= 1000);
#pragma unroll 4
    for (int kt = 0; kt < 13; ++kt) {
      int n0 = kt * 32 + kq * 8;
      int g0 = frame * 160 + n0 - 200;
      float ax[8];
      if (fvalid) {
        if (g0 >= 0 && g0 + 7 < 160000) {
          float4 u = *(const float4*)&wv[g0];
          float4 v = *(const float4*)&wv[g0 + 4];
          ax[0] = u.x; ax[1] = u.y; ax[2] = u.z; ax[3] = u.w;
          ax[4] = v.x; ax[5] = v.y; ax[6] = v.z; ax[7] = v.w;
        } else {
#pragma unroll
          for (int e = 0; e < 8; ++e) ax[e] = wv[reflect_idx(g0 + e)];
        }
      } else {
#pragma unroll
        for (int e = 0; e < 8; ++e) ax[e] = 0.0f;
      }
      float4 w0 = *(const float4*)&win[n0];
      float4 w1 = *(const float4*)&win[n0 + 4];
      uint4 pk;
      pk.x = (u32)f2bf(ax[0] * w0.x) | ((u32)f2bf(ax[1] * w0.y) << 16);
      pk.y = (u32)f2bf(ax[2] * w0.z) | ((u32)f2bf(ax[3] * w0.w) << 16);
      pk.z = (u32)f2bf(ax[4] * w1.x) | ((u32)f2bf(ax[5] * w1.y) << 16);
      pk.w = (u32)f2bf(ax[6] * w1.z) | ((u32)f2bf(ax[7] * w1.w) << 16);
      *(uint4*)(sm + kt * 8192 + kq * 2048 + rowq * 16) = pk;
    }
  }
  __syncthreads();

  // ---- GEMM1: barrier-free K-loop, 1M x 8N (13 bingroups, bins 0..207) ----
  int NG = (wid < 5) ? 2 : 1;
  int GB = (wid < 5) ? wid * 2 : wid + 5;

  f32x4 acc[8][4];
  const f32x4 zf = {0.0f, 0.0f, 0.0f, 0.0f};
#pragma unroll
  for (int mi = 0; mi < 8; ++mi)
#pragma unroll
    for (int j = 0; j < 4; ++j) acc[mi][j] = zf;

#pragma unroll
  for (int kt = 0; kt < 13; ++kt) {
    bf16x8 bfr[4];
    bfr[0] = *(const bf16x8*)(Bg + kt * 32768 + (2 * GB) * 1024 + lane * 16);
    bfr[1] = *(const bf16x8*)(Bg + kt * 32768 + (2 * GB + 1) * 1024 + lane * 16);
    if (NG == 2) {
      bfr[2] = *(const bf16x8*)(Bg + kt * 32768 + (2 * GB + 2) * 1024 + lane * 16);
      bfr[3] = *(const bf16x8*)(Bg + kt * 32768 + (2 * GB + 3) * 1024 + lane * 16);
    }
#pragma unroll
    for (int mi = 0; mi < 8; ++mi) {
      bf16x8 af = *(const bf16x8*)(sm + kt * 8192 + (lane >> 4) * 2048 +
                                   (mi * 16 + (lane & 15)) * 16);
      acc[mi][0] = __builtin_amdgcn_mfma_f32_16x16x32_bf16(af, bfr[0], acc[mi][0], 0, 0, 0);
      acc[mi][1] = __builtin_amdgcn_mfma_f32_16x16x32_bf16(af, bfr[1], acc[mi][1], 0, 0, 0);
      if (NG == 2) {
        acc[mi][2] = __builtin_amdgcn_mfma_f32_16x16x32_bf16(af, bfr[2], acc[mi][2], 0, 0, 0);
        acc[mi][3] = __builtin_amdgcn_mfma_f32_16x16x32_bf16(af, bfr[3], acc[mi][3], 0, 0, 0);
      }
    }
  }
  __syncthreads();  // all A reads done before P overwrites the region

  // ---- P = re^2+im^2 (bf16) @ LDS 0, stride 268; zero bins 208..255 ----
  u16* P = (u16*)sm;  // [128 frame][268]
#pragma unroll
  for (int j = 0; j < 2; ++j) {
    if (j < NG) {
      int bin = (GB + j) * 16 + (lane & 15);
#pragma unroll
      for (int mi = 0; mi < 8; ++mi)
#pragma unroll
        for (int r = 0; r < 4; ++r) {
          int row = mi * 16 + (lane >> 4) * 4 + r;
          float re = acc[mi][2 * j][r], im = acc[mi][2 * j + 1][r];
          P[row * P_STRIDE + bin] = f2bf(re * re + im * im);
        }
    }
  }
  {
    u32* P32 = (u32*)sm;  // zero bins 208..255 (u32 idx 104..127 per row)
    for (int i = tid; i < 3072; i += 512) {
      int row = i / 24, c = i - row * 24;
      P32[row * 134 + 104 + c] = 0;
    }
  }
  __syncthreads();

  // ---- GEMM2 (swapped): D[m][frame] = FB[m][bins] x P^T[bins][frame] ----
  f32x4 macc[4];
#pragma unroll
  for (int nf = 0; nf < 4; ++nf) macc[nf] = zf;
#pragma unroll
  for (int kt = 0; kt < 8; ++kt) {
    int krow = kt * 32 + (lane >> 4) * 8;
    bf16x8 pb = *(const bf16x8*)&P[(wid * 16 + (lane & 15)) * P_STRIDE + krow];
#pragma unroll
    for (int nf = 0; nf < 4; ++nf) {
      bf16x8 fa = *(const bf16x8*)&FBg[(nf * 16 + (lane & 15)) * 264 + krow];
      macc[nf] = __builtin_amdgcn_mfma_f32_16x16x32_bf16(fa, pb, macc[nf], 0, 0, 0);
    }
  }

  // ---- mel direct store: D col = frame, row = m ----
  int t = bx * 128 + wid * 16 + (lane & 15);
  if (t <= 1000) {
#pragma unroll
    for (int nf = 0; nf < 4; ++nf)
#pragma unroll
      for (int r = 0; r < 4; ++r) {
        int m = nf * 16 + (lane >> 4) * 4 + r;
        mel[((size_t)b * 64 + m) * MEL_STRIDE + t] = macc[nf][r];
      }
  }

  // ---- GEMM3 (fused MFCC): db = 10log10(max(mel,1e-10)) -> f16 LDS,
  //      D2[k][t] = DCT16[k][m] x db[t][m]. Wave reads only rows it wrote.
  _Float16* db = (_Float16*)(sm + 69632);  // [128 t][72] f16 (2-way conflicts)
  {
    int tl = wid * 16 + (lane & 15);  // local t row 0..127
#pragma unroll
    for (int nf = 0; nf < 4; ++nf)
#pragma unroll
      for (int r = 0; r < 4; ++r) {
        int m = nf * 16 + (lane >> 4) * 4 + r;
        float d = 10.0f * log10f(fmaxf(macc[nf][r], 1e-10f));
        db[tl * 72 + m] = (_Float16)d;
      }
    f32x4 mf0 = zf, mf1 = zf;
#pragma unroll
    for (int mkt = 0; mkt < 2; ++mkt) {
      int ms = mkt * 32 + (lane >> 4) * 8;
      f16x8 pb3 = *(const f16x8*)&db[(wid * 16 + (lane & 15)) * 72 + ms];
      f16x8 fa0 = *(const f16x8*)&DCTg[((lane & 15)) * 64 + ms];
      f16x8 fa1 = *(const f16x8*)&DCTg[(16 + (lane & 15)) * 64 + ms];
      mf0 = __builtin_amdgcn_mfma_f32_16x16x32_f16(fa0, pb3, mf0, 0, 0, 0);
      mf1 = __builtin_amdgcn_mfma_f32_16x16x32_f16(fa1, pb3, mf1, 0, 0, 0);
    }
    if (t <= 1000) {
#pragma unroll
      for (int r = 0; r < 4; ++r) {
        int k0 = (lane >> 4) * 4 + r;        // 0..15
        mfcc[((size_t)b * 20 + k0) * 1001 + t] = mf0[r];
        int k1 = 16 + (lane >> 4) * 4 + r;   // 16..31, keep <20
        if (k1 < 20)
          mfcc[((size_t)b * 20 + k1) * 1001 + t] = mf1[r];
      }
    }
  }
}

// Wave-parallel EMA scan: one wave per (b,m) row, 16 t/lane, affine map compose.
__global__ __launch_bounds__(256) void k_ema(const float* __restrict__ mel,
                                             float* __restrict__ outp) {
  int wid = threadIdx.x >> 6, lane = threadIdx.x & 63;
  int row = blockIdx.x * 4 + wid;  // 0..4095
  const float* src = mel + (size_t)row * MEL_STRIDE + lane * 16;

  float x[16];
  if (lane < 63) {
    float4 v0 = *(const float4*)&src[0];
    float4 v1 = *(const float4*)&src[4];
    float4 v2 = *(const float4*)&src[8];
    float4 v3 = *(const float4*)&src[12];
    x[0] = v0.x; x[1] = v0.y; x[2] = v0.z; x[3] = v0.w;
    x[4] = v1.x; x[5] = v1.y; x[6] = v1.z; x[7] = v1.w;
    x[8] = v2.x; x[9] = v2.y; x[10] = v2.z; x[11] = v2.w;
    x[12] = v3.x; x[13] = v3.y; x[14] = v3.z; x[15] = v3.w;
#pragma unroll
    for (int i = 0; i < 16; ++i)
      if (lane * 16 + i > 1000) x[i] = 0.0f;
  } else {
#pragma unroll
    for (int i = 0; i < 16; ++i) x[i] = 0.0f;
  }

  float B = 0.0f;
#pragma unroll
  for (int i = 0; i < 16; ++i) B = fmaf(0.98f, B, 0.02f * x[i]);
  float A = 1.0f;
#pragma unroll
  for (int i = 0; i < 16; ++i) A *= 0.98f;

#pragma unroll
  for (int d = 1; d < 64; d <<= 1) {
    float Ap = __shfl_up(A, d, 64);
    float Bp = __shfl_up(B, d, 64);
    if (lane >= d) {
      B = fmaf(A, Bp, B);
      A = A * Ap;
    }
  }
  float s = __shfl_up(B, 1, 64);
  if (lane == 0) s = 0.0f;

  float* dst = outp + (size_t)row * 1001 + lane * 16;
#pragma unroll
  for (int i = 0; i < 16; ++i) {
    s = fmaf(0.98f, s, 0.02f * x[i]);
    if (lane * 16 + i <= 1000) dst[i] = log1pf(x[i] / (s + 1e-6f));
  }
}

extern "C" void kernel_launch(void* const* d_in, const int* in_sizes, int n_in,
                              void* d_out, int out_size, void* d_ws, size_t ws_size,
                              hipStream_t stream) {
  const float* wav = (const float*)d_in[0];
  float* out = (float*)d_out;
  float* ws = (float*)d_ws;
  float* mel = ws + OFF_MEL;

  hipFuncSetAttribute(reinterpret_cast<const void*>(k_gemm),
                      hipFuncAttributeMaxDynamicSharedMemorySize, 106496);

  hipLaunchKernelGGL(k_init, dim3(64), dim3(256), 0, stream, ws);
  hipLaunchKernelGGL(k_gemm, dim3(8, 64), dim3(512), 106496, stream, wav, ws, mel,
                     out + 4100096);
  hipLaunchKernelGGL(k_ema, dim3(1024), dim3(256), 0, stream, mel, out);
}

// Round 22
// 85.719 us; speedup vs baseline: 1.3020x; 1.0486x over previous
//
#include <hip/hip_runtime.h>

#define T_FRAMES 1001
#define MEL_STRIDE 1008
#define P_STRIDE 268

// ws float offsets
#define OFF_WIN 0          // [416] f32
#define OFF_BG  1696       // u16[13 ktile][16384] twiddles, chunked (106496 f)
#define OFF_FBG 108192     // u16[64 mel][264] (8448 f)
#define OFF_DCT16 120000   // f16[32 k][64 m] DCT^T, rows 20..31 zero (1024 f)
#define OFF_MEL 13748128   // u16(bf16) [4096][1008]

typedef unsigned int u32;
typedef unsigned short u16;
typedef __attribute__((ext_vector_type(8))) short bf16x8;
typedef __attribute__((ext_vector_type(8))) _Float16 f16x8;
typedef __attribute__((ext_vector_type(4))) float f32x4;

__device__ __forceinline__ u16 f2bf(float f) {
  u32 u = __float_as_uint(f);
  u32 r = (u + 0x7FFFu + ((u >> 16) & 1u)) >> 16;
  return (u16)r;
}

__device__ __forceinline__ float bf2f(u32 h) {  // low 16 bits = bf16
  return __uint_as_float(h << 16);
}

__device__ __forceinline__ int reflect_idx(int g) {
  g = (g < 0) ? -g : g;
  g = (g >= 160000) ? (319998 - g) : g;
  return g;
}

__global__ __launch_bounds__(256) void k_init(float* __restrict__ ws) {
  float* win = ws + OFF_WIN;
  u16* bg = (u16*)(ws + OFF_BG);
  u16* fbg = (u16*)(ws + OFF_FBG);
  _Float16* dct16 = (_Float16*)(ws + OFF_DCT16);
  const float W = 6.28318530717958647692f / 400.0f;
  int tid = blockIdx.x * 256 + threadIdx.x;
  int stride = gridDim.x * 256;
  for (int i = tid; i < 416; i += stride)
    win[i] = (i < 400) ? (0.5f - 0.5f * cosf((float)i * W)) : 0.0f;
  // DCT^T in f16: [32 k-rows][64 m], rows >=20 zero (MFMA pad)
  for (int i = tid; i < 32 * 64; i += stride) {
    int k = i >> 6, m = i & 63;
    float v = 0.0f;
    if (k < 20) {
      v = cosf(3.14159265358979323846f / 64.0f * ((float)m + 0.5f) * (float)k) * sqrtf(2.0f / 64.0f);
      if (k == 0) v *= 0.70710678118654752440f;
    }
    dct16[i] = (_Float16)v;
  }
  // twiddles, chunked: u16 index = kt*16384 + g*512 + khalf*128 + c15*8 + e
  for (int i = tid; i < 13 * 16384; i += stride) {
    int kt = i >> 14;
    int r = i & 16383;
    int g = r >> 9;
    int khalf = (r >> 7) & 3;
    int c15 = (r >> 3) & 15;
    int e = r & 7;
    int col = g * 16 + c15;
    int n = kt * 32 + khalf * 8 + e;
    int bin = ((col >> 5) << 4) | (col & 15);
    int type = (col >> 4) & 1;
    float v = 0.0f;
    if (n < 400 && bin <= 200) {
      float a = (float)((n * bin) % 400) * W;
      v = type ? -sinf(a) : cosf(a);
    }
    bg[i] = f2bf(v);
  }
  // mel filterbank [mel][264], zero past bin 200
  for (int i = tid; i < 64 * 264; i += stride) {
    int m = i / 264, f = i % 264;
    float v = 0.0f;
    if (f <= 200) {
      float freq = 40.0f * (float)f;
      float m_max = 2595.0f * log10f(1.0f + 8000.0f / 700.0f);
      float ms = m_max / 65.0f;
      float fp0 = 700.0f * (powf(10.0f, (float)(m)     * ms / 2595.0f) - 1.0f);
      float fp1 = 700.0f * (powf(10.0f, (float)(m + 1) * ms / 2595.0f) - 1.0f);
      float fp2 = 700.0f * (powf(10.0f, (float)(m + 2) * ms / 2595.0f) - 1.0f);
      float dn = (freq - fp0) / (fp1 - fp0);
      float up = (fp2 - freq) / (fp2 - fp1);
      v = fmaxf(0.0f, fminf(dn, up));
    }
    fbg[i] = f2bf(v);
  }
}

// One block = 128 frames of one batch row; 512 threads = 8 waves.
// GEMM1: 1M x 8N, dead-column-trimmed. GEMM2: mel (bf16 store — mel scratch is
// consumed only by k_ema now). GEMM3: fused MFCC via f16 MFMA (r21, verified).
__global__ __launch_bounds__(512, 2) void k_gemm(const float* __restrict__ wav,
                                                 const float* __restrict__ ws,
                                                 u16* __restrict__ mel,
                                                 float* __restrict__ mfcc) {
  extern __shared__ char sm[];  // A: [13 kt][8192 B]; P overlays; db @69632
  const char* Bg = (const char*)(ws + OFF_BG);
  const u16* FBg = (const u16*)(ws + OFF_FBG);        // [64 mel][264]
  const _Float16* DCTg = (const _Float16*)(ws + OFF_DCT16);  // [32 k][64 m]
  const float* win = ws + OFF_WIN;
  int tid = threadIdx.x, wid = tid >> 6, lane = tid & 63;
  int bx = blockIdx.x, b = blockIdx.y;
  const float* wv = wav + (size_t)b * 160000;

  // ---- A build, all 13 ktiles: 4 lanes per frame row (coalesced reads) ----
  {
    int kq = tid & 3, rowq = tid >> 2;
    int frame = bx * 128 + rowq;
    bool fvalid = (frame <= 1000);
#pragma unroll 4
    for (int kt = 0; kt < 13; ++kt) {
      int n0 = kt * 32 + kq * 8;
      int g0 = frame * 160 + n0 - 200;
      float ax[8];
      if (fvalid) {
        if (g0 >= 0 && g0 + 7 < 160000) {
          float4 u = *(const float4*)&wv[g0];
          float4 v = *(const float4*)&wv[g0 + 4];
          ax[0] = u.x; ax[1] = u.y; ax[2] = u.z; ax[3] = u.w;
          ax[4] = v.x; ax[5] = v.y; ax[6] = v.z; ax[7] = v.w;
        } else {
#pragma unroll
          for (int e = 0; e < 8; ++e) ax[e] = wv[reflect_idx(g0 + e)];
        }
      } else {
#pragma unroll
        for (int e = 0; e < 8; ++e) ax[e] = 0.0f;
      }
      float4 w0 = *(const float4*)&win[n0];
      float4 w1 = *(const float4*)&win[n0 + 4];
      uint4 pk;
      pk.x = (u32)f2bf(ax[0] * w0.x) | ((u32)f2bf(ax[1] * w0.y) << 16);
      pk.y = (u32)f2bf(ax[2] * w0.z) | ((u32)f2bf(ax[3] * w0.w) << 16);
      pk.z = (u32)f2bf(ax[4] * w1.x) | ((u32)f2bf(ax[5] * w1.y) << 16);
      pk.w = (u32)f2bf(ax[6] * w1.z) | ((u32)f2bf(ax[7] * w1.w) << 16);
      *(uint4*)(sm + kt * 8192 + kq * 2048 + rowq * 16) = pk;
    }
  }
  __syncthreads();

  // ---- GEMM1: barrier-free K-loop, 1M x 8N (13 bingroups, bins 0..207) ----
  int NG = (wid < 5) ? 2 : 1;
  int GB = (wid < 5) ? wid * 2 : wid + 5;

  f32x4 acc[8][4];
  const f32x4 zf = {0.0f, 0.0f, 0.0f, 0.0f};
#pragma unroll
  for (int mi = 0; mi < 8; ++mi)
#pragma unroll
    for (int j = 0; j < 4; ++j) acc[mi][j] = zf;

#pragma unroll
  for (int kt = 0; kt < 13; ++kt) {
    bf16x8 bfr[4];
    bfr[0] = *(const bf16x8*)(Bg + kt * 32768 + (2 * GB) * 1024 + lane * 16);
    bfr[1] = *(const bf16x8*)(Bg + kt * 32768 + (2 * GB + 1) * 1024 + lane * 16);
    if (NG == 2) {
      bfr[2] = *(const bf16x8*)(Bg + kt * 32768 + (2 * GB + 2) * 1024 + lane * 16);
      bfr[3] = *(const bf16x8*)(Bg + kt * 32768 + (2 * GB + 3) * 1024 + lane * 16);
    }
#pragma unroll
    for (int mi = 0; mi < 8; ++mi) {
      bf16x8 af = *(const bf16x8*)(sm + kt * 8192 + (lane >> 4) * 2048 +
                                   (mi * 16 + (lane & 15)) * 16);
      acc[mi][0] = __builtin_amdgcn_mfma_f32_16x16x32_bf16(af, bfr[0], acc[mi][0], 0, 0, 0);
      acc[mi][1] = __builtin_amdgcn_mfma_f32_16x16x32_bf16(af, bfr[1], acc[mi][1], 0, 0, 0);
      if (NG == 2) {
        acc[mi][2] = __builtin_amdgcn_mfma_f32_16x16x32_bf16(af, bfr[2], acc[mi][2], 0, 0, 0);
        acc[mi][3] = __builtin_amdgcn_mfma_f32_16x16x32_bf16(af, bfr[3], acc[mi][3], 0, 0, 0);
      }
    }
  }
  __syncthreads();  // all A reads done before P overwrites the region

  // ---- P = re^2+im^2 (bf16) @ LDS 0, stride 268; zero bins 208..255 ----
  u16* P = (u16*)sm;  // [128 frame][268]
#pragma unroll
  for (int j = 0; j < 2; ++j) {
    if (j < NG) {
      int bin = (GB + j) * 16 + (lane & 15);
#pragma unroll
      for (int mi = 0; mi < 8; ++mi)
#pragma unroll
        for (int r = 0; r < 4; ++r) {
          int row = mi * 16 + (lane >> 4) * 4 + r;
          float re = acc[mi][2 * j][r], im = acc[mi][2 * j + 1][r];
          P[row * P_STRIDE + bin] = f2bf(re * re + im * im);
        }
    }
  }
  {
    u32* P32 = (u32*)sm;  // zero bins 208..255 (u32 idx 104..127 per row)
    for (int i = tid; i < 3072; i += 512) {
      int row = i / 24, c = i - row * 24;
      P32[row * 134 + 104 + c] = 0;
    }
  }
  __syncthreads();

  // ---- GEMM2 (swapped): D[m][frame] = FB[m][bins] x P^T[bins][frame] ----
  f32x4 macc[4];
#pragma unroll
  for (int nf = 0; nf < 4; ++nf) macc[nf] = zf;
#pragma unroll
  for (int kt = 0; kt < 8; ++kt) {
    int krow = kt * 32 + (lane >> 4) * 8;
    bf16x8 pb = *(const bf16x8*)&P[(wid * 16 + (lane & 15)) * P_STRIDE + krow];
#pragma unroll
    for (int nf = 0; nf < 4; ++nf) {
      bf16x8 fa = *(const bf16x8*)&FBg[(nf * 16 + (lane & 15)) * 264 + krow];
      macc[nf] = __builtin_amdgcn_mfma_f32_16x16x32_bf16(fa, pb, macc[nf], 0, 0, 0);
    }
  }

  // ---- mel direct store (bf16): D col = frame, row = m ----
  int t = bx * 128 + wid * 16 + (lane & 15);
  if (t <= 1000) {
#pragma unroll
    for (int nf = 0; nf < 4; ++nf)
#pragma unroll
      for (int r = 0; r < 4; ++r) {
        int m = nf * 16 + (lane >> 4) * 4 + r;
        mel[((size_t)b * 64 + m) * MEL_STRIDE + t] = f2bf(macc[nf][r]);
      }
  }

  // ---- GEMM3 (fused MFCC): db = 10log10(max(mel,1e-10)) -> f16 LDS,
  //      D2[k][t] = DCT16[k][m] x db[t][m]. Wave reads only rows it wrote.
  _Float16* db = (_Float16*)(sm + 69632);  // [128 t][72] f16 (2-way conflicts)
  {
    int tl = wid * 16 + (lane & 15);  // local t row 0..127
#pragma unroll
    for (int nf = 0; nf < 4; ++nf)
#pragma unroll
      for (int r = 0; r < 4; ++r) {
        int m = nf * 16 + (lane >> 4) * 4 + r;
        float d = 10.0f * log10f(fmaxf(macc[nf][r], 1e-10f));
        db[tl * 72 + m] = (_Float16)d;
      }
    f32x4 mf0 = zf, mf1 = zf;
#pragma unroll
    for (int mkt = 0; mkt < 2; ++mkt) {
      int ms = mkt * 32 + (lane >> 4) * 8;
      f16x8 pb3 = *(const f16x8*)&db[(wid * 16 + (lane & 15)) * 72 + ms];
      f16x8 fa0 = *(const f16x8*)&DCTg[((lane & 15)) * 64 + ms];
      f16x8 fa1 = *(const f16x8*)&DCTg[(16 + (lane & 15)) * 64 + ms];
      mf0 = __builtin_amdgcn_mfma_f32_16x16x32_f16(fa0, pb3, mf0, 0, 0, 0);
      mf1 = __builtin_amdgcn_mfma_f32_16x16x32_f16(fa1, pb3, mf1, 0, 0, 0);
    }
    if (t <= 1000) {
#pragma unroll
      for (int r = 0; r < 4; ++r) {
        int k0 = (lane >> 4) * 4 + r;        // 0..15
        mfcc[((size_t)b * 20 + k0) * 1001 + t] = mf0[r];
        int k1 = 16 + (lane >> 4) * 4 + r;   // 16..31, keep <20
        if (k1 < 20)
          mfcc[((size_t)b * 20 + k1) * 1001 + t] = mf1[r];
      }
    }
  }
}

// Wave-parallel EMA scan: one wave per (b,m) row, 16 t/lane (bf16 input),
// affine map compose via shuffle scan.
__global__ __launch_bounds__(256) void k_ema(const u16* __restrict__ mel,
                                             float* __restrict__ outp) {
  int wid = threadIdx.x >> 6, lane = threadIdx.x & 63;
  int row = blockIdx.x * 4 + wid;  // 0..4095
  const u16* src = mel + (size_t)row * MEL_STRIDE + lane * 16;

  float x[16];
  if (lane < 63) {
    uint4 v0 = *(const uint4*)&src[0];  // 8 bf16
    uint4 v1 = *(const uint4*)&src[8];  // 8 bf16
    x[0] = bf2f(v0.x & 0xFFFF);  x[1] = bf2f(v0.x >> 16);
    x[2] = bf2f(v0.y & 0xFFFF);  x[3] = bf2f(v0.y >> 16);
    x[4] = bf2f(v0.z & 0xFFFF);  x[5] = bf2f(v0.z >> 16);
    x[6] = bf2f(v0.w & 0xFFFF);  x[7] = bf2f(v0.w >> 16);
    x[8] = bf2f(v1.x & 0xFFFF);  x[9] = bf2f(v1.x >> 16);
    x[10] = bf2f(v1.y & 0xFFFF); x[11] = bf2f(v1.y >> 16);
    x[12] = bf2f(v1.z & 0xFFFF); x[13] = bf2f(v1.z >> 16);
    x[14] = bf2f(v1.w & 0xFFFF); x[15] = bf2f(v1.w >> 16);
#pragma unroll
    for (int i = 0; i < 16; ++i)
      if (lane * 16 + i > 1000) x[i] = 0.0f;
  } else {
#pragma unroll
    for (int i = 0; i < 16; ++i) x[i] = 0.0f;
  }

  float B = 0.0f;
#pragma unroll
  for (int i = 0; i < 16; ++i) B = fmaf(0.98f, B, 0.02f * x[i]);
  float A = 1.0f;
#pragma unroll
  for (int i = 0; i < 16; ++i) A *= 0.98f;

#pragma unroll
  for (int d = 1; d < 64; d <<= 1) {
    float Ap = __shfl_up(A, d, 64);
    float Bp = __shfl_up(B, d, 64);
    if (lane >= d) {
      B = fmaf(A, Bp, B);
      A = A * Ap;
    }
  }
  float s = __shfl_up(B, 1, 64);
  if (lane == 0) s = 0.0f;

  float* dst = outp + (size_t)row * 1001 + lane * 16;
#pragma unroll
  for (int i = 0; i < 16; ++i) {
    s = fmaf(0.98f, s, 0.02f * x[i]);
    if (lane * 16 + i <= 1000) dst[i] = log1pf(x[i] / (s + 1e-6f));
  }
}

extern "C" void kernel_launch(void* const* d_in, const int* in_sizes, int n_in,
                              void* d_out, int out_size, void* d_ws, size_t ws_size,
                              hipStream_t stream) {
  const float* wav = (const float*)d_in[0];
  float* out = (float*)d_out;
  float* ws = (float*)d_ws;
  u16* mel = (u16*)(ws + OFF_MEL);

  hipFuncSetAttribute(reinterpret_cast<const void*>(k_gemm),
                      hipFuncAttributeMaxDynamicSharedMemorySize, 106496);

  hipLaunchKernelGGL(k_init, dim3(256), dim3(256), 0, stream, ws);
  hipLaunchKernelGGL(k_gemm, dim3(8, 64), dim3(512), 106496, stream, wav, ws, mel,
                     out + 4100096);
  hipLaunchKernelGGL(k_ema, dim3(1024), dim3(256), 0, stream, mel, out);
}